// Round 2
// baseline (1626.157 us; speedup 1.0000x reference)
//
#include <hip/hip_runtime.h>

#define CODE_DIM 256
#define KCODES   1024
#define NT       32      // queries per block
#define KT       512     // k-tile per kt iteration
#define CC       8       // c-chunk
#define GSTR     12      // dwords per 8-float group (8 data + 4 pad) -> 2-way max bank aliasing
#define ZROW     48      // 4 n-groups * GSTR
#define WROW     768     // 64 k-groups * GSTR
#define OUTHALF  8388608

__global__ __launch_bounds__(256, 4) void vq_kernel(
    const float* __restrict__ z,    // [32,256,32,32]
    const float* __restrict__ w,    // [1024,256]
    float* __restrict__ out)        // code | detached | idx(float)
{
    __shared__ float zt[CC][ZROW];
    __shared__ float wt[CC][WROW];
    __shared__ float w2s[KCODES];
    __shared__ float gb[32][36];
    __shared__ float redv[4][NT];
    __shared__ int   redi[4][NT];
    __shared__ int   idxb[NT];

    const int t = threadIdx.x;

    // ---- ||w_k||^2 (sequential over c, same order as passing round-1 kernel)
    for (int kk = t; kk < KCODES; kk += 256) {
        const float4* row = reinterpret_cast<const float4*>(w + (size_t)kk * CODE_DIM);
        float s = 0.0f;
        #pragma unroll 4
        for (int c4 = 0; c4 < 64; ++c4) {
            float4 v = row[c4];
            s += v.x * v.x;
            s += v.y * v.y;
            s += v.z * v.z;
            s += v.w * v.w;
        }
        w2s[kk] = s;
    }

    const int n0  = blockIdx.x * NT;
    const int b   = n0 >> 10;
    const int hw0 = n0 & 1023;
    const float* zb = z + (size_t)b * (CODE_DIM * 1024) + hw0;

    const int ng = t & 3;        // n-group (8 n each)
    const int kg = t >> 2;       // k-group 0..63 (8 k each)
    const float* ztp = &zt[0][ng * GSTR];
    const float* wtp = &wt[0][kg * GSTR];

    float rmin[8], z2[8];
    int   ridx[8];
    #pragma unroll
    for (int i = 0; i < 8; ++i) { rmin[i] = 3.4e38f; ridx[i] = 0; z2[i] = 0.0f; }

    for (int kt = 0; kt < 2; ++kt) {
        float acc[8][8];
        #pragma unroll
        for (int i = 0; i < 8; ++i)
            #pragma unroll
            for (int j = 0; j < 8; ++j) acc[i][j] = 0.0f;

        for (int ct = 0; ct < 32; ++ct) {
            __syncthreads();
            // stage z chunk: 8c x 32n (wave 0 only; tiny)
            if (t < 64) {
                int c = t >> 3, f4 = t & 7;
                float4 v = *reinterpret_cast<const float4*>(
                    zb + (size_t)(ct * CC + c) * 1024 + f4 * 4);
                *reinterpret_cast<float4*>(&zt[c][(f4 >> 1) * GSTR + (f4 & 1) * 4]) = v;
            }
            // stage w chunk transposed: 8c x 512k, group-padded (<=2-way write conflicts)
            #pragma unroll
            for (int r = 0; r < 4; ++r) {
                int kl = (t >> 1) + r * 128;
                int c4 = (t & 1) * 4;
                float4 v = *reinterpret_cast<const float4*>(
                    w + (size_t)(kt * KT + kl) * CODE_DIM + ct * CC + c4);
                int goff = (kl >> 3) * GSTR + (kl & 7);
                wt[c4 + 0][goff] = v.x;
                wt[c4 + 1][goff] = v.y;
                wt[c4 + 2][goff] = v.z;
                wt[c4 + 3][goff] = v.w;
            }
            __syncthreads();

            if (kt == 0) {
                #pragma unroll
                for (int c = 0; c < CC; ++c) {
                    float4 za = *reinterpret_cast<const float4*>(ztp + c * ZROW);
                    float4 zc = *reinterpret_cast<const float4*>(ztp + c * ZROW + 4);
                    float4 wa = *reinterpret_cast<const float4*>(wtp + c * WROW);
                    float4 wc = *reinterpret_cast<const float4*>(wtp + c * WROW + 4);
                    float zr[8] = {za.x, za.y, za.z, za.w, zc.x, zc.y, zc.z, zc.w};
                    float wr[8] = {wa.x, wa.y, wa.z, wa.w, wc.x, wc.y, wc.z, wc.w};
                    #pragma unroll
                    for (int i = 0; i < 8; ++i) {
                        #pragma unroll
                        for (int j = 0; j < 8; ++j) acc[i][j] += zr[i] * wr[j];
                        z2[i] += zr[i] * zr[i];
                    }
                }
            } else {
                #pragma unroll
                for (int c = 0; c < CC; ++c) {
                    float4 za = *reinterpret_cast<const float4*>(ztp + c * ZROW);
                    float4 zc = *reinterpret_cast<const float4*>(ztp + c * ZROW + 4);
                    float4 wa = *reinterpret_cast<const float4*>(wtp + c * WROW);
                    float4 wc = *reinterpret_cast<const float4*>(wtp + c * WROW + 4);
                    float zr[8] = {za.x, za.y, za.z, za.w, zc.x, zc.y, zc.z, zc.w};
                    float wr[8] = {wa.x, wa.y, wa.z, wa.w, wc.x, wc.y, wc.z, wc.w};
                    #pragma unroll
                    for (int i = 0; i < 8; ++i)
                        #pragma unroll
                        for (int j = 0; j < 8; ++j) acc[i][j] += zr[i] * wr[j];
                }
            }
        }

        // finalize k-tile: dist = fl(fl(z2 - 2*dot) + w2); per-thread k ascending
        #pragma unroll
        for (int j = 0; j < 8; ++j) {
            int kk = kt * KT + kg * 8 + j;
            float w2v = w2s[kk];
            #pragma unroll
            for (int i = 0; i < 8; ++i) {
                float d = (z2[i] - 2.0f * acc[i][j]) + w2v;
                if (d < rmin[i]) { rmin[i] = d; ridx[i] = kk; }
            }
        }
    }

    // ---- argmin reduce: butterfly over lanes sharing (lane&3), then cross-wave via LDS
    #pragma unroll
    for (int m = 4; m <= 32; m <<= 1) {
        #pragma unroll
        for (int i = 0; i < 8; ++i) {
            float vo = __shfl_xor(rmin[i], m, 64);
            int   io = __shfl_xor(ridx[i], m, 64);
            if (vo < rmin[i] || (vo == rmin[i] && io < ridx[i])) { rmin[i] = vo; ridx[i] = io; }
        }
    }
    {
        const int lane = t & 63, wvid = t >> 6;
        if (lane < 4) {
            #pragma unroll
            for (int i = 0; i < 8; ++i) {
                redv[wvid][lane * 8 + i] = rmin[i];
                redi[wvid][lane * 8 + i] = ridx[i];
            }
        }
    }
    __syncthreads();
    if (t < NT) {
        float bv = redv[0][t]; int bi = redi[0][t];
        #pragma unroll
        for (int q = 1; q < 4; ++q) {
            float v = redv[q][t]; int ii = redi[q][t];
            if (v < bv || (v == bv && ii < bi)) { bv = v; bi = ii; }
        }
        idxb[t] = bi;
        out[(size_t)2 * OUTHALF + n0 + t] = (float)bi;
    }
    __syncthreads();

    // ---- gather + transpose epilogue
    float* out0 = out;
    float* out1 = out + OUTHALF;
    const size_t obase = (size_t)b * (CODE_DIM * 1024) + hw0;

    for (int ct = 0; ct < 8; ++ct) {
        {
            int n = t & 31, seg = t >> 5;
            int kk = idxb[n];
            float4 v = *reinterpret_cast<const float4*>(
                w + (size_t)kk * CODE_DIM + ct * 32 + seg * 4);
            gb[seg * 4 + 0][n] = v.x;
            gb[seg * 4 + 1][n] = v.y;
            gb[seg * 4 + 2][n] = v.z;
            gb[seg * 4 + 3][n] = v.w;
        }
        __syncthreads();
        {
            int c = t >> 3, f4 = t & 7;
            float4 cv = *reinterpret_cast<const float4*>(&gb[c][f4 * 4]);
            size_t off = (size_t)(ct * 32 + c) * 1024 + f4 * 4;
            float4 zz = *reinterpret_cast<const float4*>(zb + off);
            float4 o1;
            o1.x = (cv.x - zz.x) + zz.x;
            o1.y = (cv.y - zz.y) + zz.y;
            o1.z = (cv.z - zz.z) + zz.z;
            o1.w = (cv.w - zz.w) + zz.w;
            *reinterpret_cast<float4*>(out0 + obase + off) = cv;
            *reinterpret_cast<float4*>(out1 + obase + off) = o1;
        }
        __syncthreads();
    }
}

extern "C" void kernel_launch(void* const* d_in, const int* in_sizes, int n_in,
                              void* d_out, int out_size, void* d_ws, size_t ws_size,
                              hipStream_t stream) {
    const float* z = (const float*)d_in[0];
    const float* w = (const float*)d_in[1];
    float* out = (float*)d_out;
    vq_kernel<<<1024, 256, 0, stream>>>(z, w, out);
}

// Round 3
// 316.899 us; speedup vs baseline: 5.1315x; 5.1315x over previous
//
#include <hip/hip_runtime.h>

#define OUTHALF 8388608

// Layout / tiling:
//   grid = 512 blocks, 256 threads. Block owns NT=64 queries (n) and all K=1024 codes.
//   4 k-passes of 256 k; per pass 8 c-chunks of 32 c staged in LDS.
//   Thread micro-tile: 8 n x 8 k.  ng = t>>5 (8 groups), kg = t&31 (32 groups).
//   wt row stride 322 dwords (32 k-groups * 10 + 2): 8B-aligned groups, <=2-way banks.
//   zt row stride 66: 8B-aligned, reads are 2-address broadcasts (conflict-free).
__global__ __launch_bounds__(256) void vq_kernel(
    const float* __restrict__ z,    // [32,256,32,32]
    const float* __restrict__ w,    // [1024,256]
    float* __restrict__ out)        // code(8388608) | detached(8388608) | idx(32768) as float
{
    __shared__ float wt[32][322];   // 41216 B
    __shared__ float zt[32][66];    //  8448 B
    __shared__ float w2s[1024];     //  4096 B
    __shared__ int   idxb[64];      //   256 B   (total 54016 B)

    const int t = threadIdx.x;

    // ---- ||w_k||^2, sequential over c (same rounding chain as passing rounds)
    for (int kk = t; kk < 1024; kk += 256) {
        const float4* row = reinterpret_cast<const float4*>(w + (size_t)kk * 256);
        float s = 0.0f;
        #pragma unroll 4
        for (int c4 = 0; c4 < 64; ++c4) {
            float4 v = row[c4];
            s += v.x * v.x;
            s += v.y * v.y;
            s += v.z * v.z;
            s += v.w * v.w;
        }
        w2s[kk] = s;
    }

    const int n0  = blockIdx.x * 64;
    const int b   = n0 >> 10;
    const int hw0 = n0 & 1023;
    const float* zb = z + (size_t)b * (256 * 1024) + hw0;

    const int ng = t >> 5;
    const int kg = t & 31;
    const float* wtp = &wt[0][0] + kg * 10;
    const float* ztp = &zt[0][0] + ng * 8;

    float rmin[8], z2v[8];
    int   ridx[8];
    #pragma unroll
    for (int i = 0; i < 8; ++i) { rmin[i] = 3.4e38f; ridx[i] = 0; z2v[i] = 0.0f; }

    for (int kt = 0; kt < 4; ++kt) {
        float acc[8][8];
        #pragma unroll
        for (int i = 0; i < 8; ++i)
            #pragma unroll
            for (int j = 0; j < 8; ++j) acc[i][j] = 0.0f;

        for (int ct = 0; ct < 8; ++ct) {
            __syncthreads();
            // stage w chunk: 256 k x 32 c, transposed into wt[c][kgroup*10 + j]
            #pragma unroll
            for (int r = 0; r < 8; ++r) {
                int k  = r * 32 + (t >> 3);
                int c4 = t & 7;
                float4 v = *reinterpret_cast<const float4*>(
                    w + (size_t)(kt * 256 + k) * 256 + ct * 32 + c4 * 4);
                int goff = (k >> 3) * 10 + (k & 7);
                wt[c4 * 4 + 0][goff] = v.x;
                wt[c4 * 4 + 1][goff] = v.y;
                wt[c4 * 4 + 2][goff] = v.z;
                wt[c4 * 4 + 3][goff] = v.w;
            }
            // stage z chunk: 32 c x 64 n
            #pragma unroll
            for (int r = 0; r < 2; ++r) {
                int c  = r * 16 + (t >> 4);
                int n4 = t & 15;
                float4 v = *reinterpret_cast<const float4*>(
                    zb + (size_t)(ct * 32 + c) * 1024 + n4 * 4);
                zt[c][n4 * 4 + 0] = v.x;
                zt[c][n4 * 4 + 1] = v.y;
                zt[c][n4 * 4 + 2] = v.z;
                zt[c][n4 * 4 + 3] = v.w;
            }
            __syncthreads();

            if (kt == 0) {
                #pragma unroll 4
                for (int c = 0; c < 32; ++c) {
                    const float* zp = ztp + c * 66;
                    const float* wp = wtp + c * 322;
                    float2 z0 = *reinterpret_cast<const float2*>(zp);
                    float2 z1 = *reinterpret_cast<const float2*>(zp + 2);
                    float2 z2 = *reinterpret_cast<const float2*>(zp + 4);
                    float2 z3 = *reinterpret_cast<const float2*>(zp + 6);
                    float2 w0 = *reinterpret_cast<const float2*>(wp);
                    float2 w1 = *reinterpret_cast<const float2*>(wp + 2);
                    float2 w2 = *reinterpret_cast<const float2*>(wp + 4);
                    float2 w3 = *reinterpret_cast<const float2*>(wp + 6);
                    float zr[8] = {z0.x, z0.y, z1.x, z1.y, z2.x, z2.y, z3.x, z3.y};
                    float wr[8] = {w0.x, w0.y, w1.x, w1.y, w2.x, w2.y, w3.x, w3.y};
                    #pragma unroll
                    for (int i = 0; i < 8; ++i) {
                        #pragma unroll
                        for (int j = 0; j < 8; ++j) acc[i][j] += zr[i] * wr[j];
                        z2v[i] += zr[i] * zr[i];
                    }
                }
            } else {
                #pragma unroll 4
                for (int c = 0; c < 32; ++c) {
                    const float* zp = ztp + c * 66;
                    const float* wp = wtp + c * 322;
                    float2 z0 = *reinterpret_cast<const float2*>(zp);
                    float2 z1 = *reinterpret_cast<const float2*>(zp + 2);
                    float2 z2 = *reinterpret_cast<const float2*>(zp + 4);
                    float2 z3 = *reinterpret_cast<const float2*>(zp + 6);
                    float2 w0 = *reinterpret_cast<const float2*>(wp);
                    float2 w1 = *reinterpret_cast<const float2*>(wp + 2);
                    float2 w2 = *reinterpret_cast<const float2*>(wp + 4);
                    float2 w3 = *reinterpret_cast<const float2*>(wp + 6);
                    float zr[8] = {z0.x, z0.y, z1.x, z1.y, z2.x, z2.y, z3.x, z3.y};
                    float wr[8] = {w0.x, w0.y, w1.x, w1.y, w2.x, w2.y, w3.x, w3.y};
                    #pragma unroll
                    for (int i = 0; i < 8; ++i)
                        #pragma unroll
                        for (int j = 0; j < 8; ++j) acc[i][j] += zr[i] * wr[j];
                }
            }
        }

        // finalize pass: dist = fl(fl(z2 - 2*dot) + w2); per-thread k ascending over (kt, j)
        #pragma unroll
        for (int j = 0; j < 8; ++j) {
            int kk = kt * 256 + kg * 8 + j;
            float w2v = w2s[kk];
            #pragma unroll
            for (int i = 0; i < 8; ++i) {
                float d = (z2v[i] - 2.0f * acc[i][j]) + w2v;
                if (d < rmin[i]) { rmin[i] = d; ridx[i] = kk; }
            }
        }
    }

    // ---- argmin reduce across kg (lanes 0..31 within half-wave), index tie-break
    #pragma unroll
    for (int m = 1; m <= 16; m <<= 1) {
        #pragma unroll
        for (int i = 0; i < 8; ++i) {
            float vo = __shfl_xor(rmin[i], m, 64);
            int   io = __shfl_xor(ridx[i], m, 64);
            if (vo < rmin[i] || (vo == rmin[i] && io < ridx[i])) { rmin[i] = vo; ridx[i] = io; }
        }
    }
    if (kg == 0) {
        #pragma unroll
        for (int i = 0; i < 8; ++i) {
            idxb[ng * 8 + i] = ridx[i];
            out[(size_t)2 * OUTHALF + n0 + ng * 8 + i] = (float)ridx[i];
        }
    }

    // ---- gather + transpose epilogue (round-1 verbatim; gbuf aliases wt)
    float (*gbuf)[68] = reinterpret_cast<float (*)[68]>(&wt[0][0]);
    float* out0 = out;
    float* out1 = out + OUTHALF;
    const size_t obase = (size_t)b * (256 * 1024) + hw0;

    for (int ct = 0; ct < 4; ++ct) {
        __syncthreads();
        {
            int n = t & 63, seg = t >> 6;
            int kk = idxb[n];
            #pragma unroll
            for (int u = 0; u < 4; ++u) {
                int c = seg * 16 + u * 4;
                float4 v = *reinterpret_cast<const float4*>(
                    w + (size_t)kk * 256 + ct * 64 + c);
                gbuf[c + 0][n] = v.x;
                gbuf[c + 1][n] = v.y;
                gbuf[c + 2][n] = v.z;
                gbuf[c + 3][n] = v.w;
            }
        }
        __syncthreads();
        #pragma unroll
        for (int p = 0; p < 16; ++p) {
            int c = p * 4 + (t >> 6);
            int n = t & 63;
            float cv = gbuf[c][n];
            size_t off = (size_t)(ct * 64 + c) * 1024 + n;
            float zz = zb[off];
            out0[obase + off] = cv;
            out1[obase + off] = (cv - zz) + zz;   // replicate reference rounding chain
        }
    }
}

extern "C" void kernel_launch(void* const* d_in, const int* in_sizes, int n_in,
                              void* d_out, int out_size, void* d_ws, size_t ws_size,
                              hipStream_t stream) {
    const float* z = (const float*)d_in[0];
    const float* w = (const float*)d_in[1];
    float* out = (float*)d_out;
    vq_kernel<<<512, 256, 0, stream>>>(z, w, out);
}